// Round 2
// baseline (427.482 us; speedup 1.0000x reference)
//
#include <hip/hip_runtime.h>
#include <hip/hip_bf16.h>
#include <math.h>

// Deformable DETR multi-scale deformable attention — MI355X (gfx950)
// B=2, Lq=Lv=13294, D=256, H=8, HD=32, L=4, P=4
// Levels: (100,100),(50,50),(25,25),(13,13)  starts {0,10000,12500,13125}

namespace {
constexpr int LQ    = 13294;
constexpr int LV    = 13294;
constexpr int NL    = 4;
constexpr int NROWS = 2 * LQ;   // B * Lq = 26588
}

typedef __attribute__((ext_vector_type(8))) short short8;   // 8 x bf16 (4 VGPRs)
typedef __attribute__((ext_vector_type(4))) float f32x4;    // MFMA accumulator

__device__ __constant__ int c_lw[4] = {100, 50, 25, 13};

__device__ inline short f2bfbits(float f) {
    __hip_bfloat16 h = __float2bfloat16(f);
    return *reinterpret_cast<short*>(&h);
}

// ---------------------------------------------------------------------------
// W[256][256] fp32 -> WT[col][k] bf16 (transposed, MFMA-B friendly)
// ---------------------------------------------------------------------------
__global__ __launch_bounds__(256) void transpose_w(
    const float* __restrict__ W, __hip_bfloat16* __restrict__ WT)
{
    const int c = blockIdx.x;    // column of W
    const int k = threadIdx.x;   // row of W
    WT[c * 256 + k] = __float2bfloat16(W[k * 256 + c]);
}

// ---------------------------------------------------------------------------
// MFMA GEMM: Y[M][256] = X[M][256] @ W[256][256] + bias
// WT is bf16 [col][k]. A_FP32: X is fp32 (convert on the fly) else bf16.
// OUT_BF16: Y stored bf16, else fp32.
// Block: 256 thr = 4 waves; block owns 16 rows, wave w owns cols w*64..+63
// (4 n-tiles of 16), K=256 in 8 chunks of 32.
// ---------------------------------------------------------------------------
template<bool A_FP32, bool OUT_BF16>
__global__ __launch_bounds__(256) void gemm_mfma(
    const void* __restrict__ Xv, const __hip_bfloat16* __restrict__ WT,
    const float* __restrict__ bias, void* __restrict__ Yv, int M)
{
    const int lane = threadIdx.x & 63;
    const int wv   = threadIdx.x >> 6;
    const int r0   = blockIdx.x * 16;
    const int r16  = lane & 15;
    const int koff = (lane >> 4) * 8;
    const int c0   = wv * 64;
    const int row  = r0 + r16;
    const bool rvalid = (row < M);

    f32x4 acc[4] = {{0.f,0.f,0.f,0.f},{0.f,0.f,0.f,0.f},
                    {0.f,0.f,0.f,0.f},{0.f,0.f,0.f,0.f}};

    #pragma unroll
    for (int kc = 0; kc < 8; ++kc) {
        short8 afrag;
        if (A_FP32) {
            const float* xp = (const float*)Xv + (size_t)row * 256 + kc * 32 + koff;
            float4 u0, u1;
            if (rvalid) { u0 = *(const float4*)xp; u1 = *(const float4*)(xp + 4); }
            else        { u0 = make_float4(0,0,0,0); u1 = u0; }
            afrag[0] = f2bfbits(u0.x); afrag[1] = f2bfbits(u0.y);
            afrag[2] = f2bfbits(u0.z); afrag[3] = f2bfbits(u0.w);
            afrag[4] = f2bfbits(u1.x); afrag[5] = f2bfbits(u1.y);
            afrag[6] = f2bfbits(u1.z); afrag[7] = f2bfbits(u1.w);
        } else {
            const __hip_bfloat16* xp =
                (const __hip_bfloat16*)Xv + (size_t)row * 256 + kc * 32 + koff;
            if (rvalid) afrag = *(const short8*)xp;
            else { short8 z = {0,0,0,0,0,0,0,0}; afrag = z; }
        }
        #pragma unroll
        for (int nt = 0; nt < 4; ++nt) {
            const int col = c0 + nt * 16 + r16;
            short8 bfrag = *(const short8*)(WT + (size_t)col * 256 + kc * 32 + koff);
            acc[nt] = __builtin_amdgcn_mfma_f32_16x16x32_bf16(afrag, bfrag, acc[nt], 0, 0, 0);
        }
    }

    const int orow0 = r0 + (lane >> 4) * 4;
    #pragma unroll
    for (int nt = 0; nt < 4; ++nt) {
        const int col = c0 + nt * 16 + r16;
        const float bb = bias[col];
        #pragma unroll
        for (int j = 0; j < 4; ++j) {
            const int rr = orow0 + j;
            if (rr < M) {
                const float v = acc[nt][j] + bb;
                if (OUT_BF16)
                    ((__hip_bfloat16*)Yv)[(size_t)rr * 256 + col] = __float2bfloat16(v);
                else
                    ((float*)Yv)[(size_t)rr * 256 + col] = v;
            }
        }
    }
}

// ---------------------------------------------------------------------------
// Fused: off = q@W_off+b_off ; logits = q@W_attn+b_attn ; softmax(16/head) ;
// sampling coords x = (ref + off/w)*w - 0.5 stored [row][128][2]. fp32 exact.
// 8 query rows per block. (unchanged from R0 — numerics control)
// ---------------------------------------------------------------------------
__global__ __launch_bounds__(256) void off_attn_loc(
    const float* __restrict__ query, const float* __restrict__ refpts,
    const float* __restrict__ Woff,  const float* __restrict__ boff,
    const float* __restrict__ Wattn, const float* __restrict__ battn,
    float* __restrict__ sloc, float* __restrict__ awout)
{
    __shared__ float qs[8][256];
    __shared__ float offs[8][256];
    const int tid = threadIdx.x;
    const int r0  = blockIdx.x * 8;

    for (int i = tid; i < 8 * 256; i += 256) {
        const int r = i >> 8, k = i & 255;
        const int row = r0 + r;
        qs[r][k] = (row < NROWS) ? query[(size_t)row * 256 + k] : 0.0f;
    }
    __syncthreads();

    {
        float acc[8] = {0.f,0.f,0.f,0.f,0.f,0.f,0.f,0.f};
        #pragma unroll 4
        for (int k = 0; k < 256; ++k) {
            const float w = Woff[(size_t)k * 256 + tid];
            #pragma unroll
            for (int r = 0; r < 8; ++r) acc[r] = fmaf(qs[r][k], w, acc[r]);
        }
        const float bb = boff[tid];
        #pragma unroll
        for (int r = 0; r < 8; ++r) offs[r][tid] = acc[r] + bb;
    }

    float accA[8] = {0.f,0.f,0.f,0.f,0.f,0.f,0.f,0.f};
    if (tid < 128) {
        #pragma unroll 4
        for (int k = 0; k < 256; ++k) {
            const float w = Wattn[(size_t)k * 128 + tid];
            #pragma unroll
            for (int r = 0; r < 8; ++r) accA[r] = fmaf(qs[r][k], w, accA[r]);
        }
    }
    __syncthreads();

    if (tid < 128) {
        const float ba = battn[tid];
        const int   l  = (tid >> 2) & 3;
        const float wl = (float)c_lw[l];
        #pragma unroll
        for (int r = 0; r < 8; ++r) {
            const int row = r0 + r;
            if (row >= NROWS) break;
            const float v = accA[r] + ba;
            float m = v;
            #pragma unroll
            for (int o = 8; o > 0; o >>= 1) m = fmaxf(m, __shfl_xor(m, o, 16));
            const float e = expf(v - m);
            float ssum = e;
            #pragma unroll
            for (int o = 8; o > 0; o >>= 1) ssum += __shfl_xor(ssum, o, 16);
            awout[(size_t)row * 128 + tid] = e / ssum;
            const float ox = offs[r][2 * tid];
            const float oy = offs[r][2 * tid + 1];
            const float rx = refpts[((size_t)row * NL + l) * 2 + 0];
            const float ry = refpts[((size_t)row * NL + l) * 2 + 1];
            sloc[(size_t)row * 256 + 2 * tid]     = (rx + ox / wl) * wl - 0.5f;
            sloc[(size_t)row * 256 + 2 * tid + 1] = (ry + oy / wl) * wl - 0.5f;
        }
    }
}

// ---------------------------------------------------------------------------
// Bilinear sampling + attention-weighted sum, bf16 vproj, bf16 out.
// Block = 256 thr = 8 rows x 32 lanes; lane = h*4 + c8 (8 channels each).
// ---------------------------------------------------------------------------
__device__ inline void fma8(float* acc, uint4 q, float w) {
    const unsigned u[4] = {q.x, q.y, q.z, q.w};
    #pragma unroll
    for (int i = 0; i < 4; ++i) {
        const float lo = __uint_as_float(u[i] << 16);
        const float hi = __uint_as_float(u[i] & 0xffff0000u);
        acc[2*i]   = fmaf(lo, w, acc[2*i]);
        acc[2*i+1] = fmaf(hi, w, acc[2*i+1]);
    }
}

__global__ __launch_bounds__(256) void ms_sample(
    const __hip_bfloat16* __restrict__ vproj, const float* __restrict__ sloc,
    const float* __restrict__ aw, __hip_bfloat16* __restrict__ sampled)
{
    __shared__ float sxy[8][256];
    __shared__ float sw[8][128];
    const int tid = threadIdx.x;
    const int r0  = blockIdx.x * 8;

    {   // stage sloc (2048 floats) + aw (1024 floats), guarded for tail block
        const int limS = (NROWS - r0) * 256;
        const float* src = sloc + (size_t)r0 * 256;
        #pragma unroll
        for (int i = tid * 4; i < 2048; i += 1024) {
            float4 v = (i < limS) ? *(const float4*)(src + i) : make_float4(0,0,0,0);
            *(float4*)(&sxy[0][0] + i) = v;
        }
        const int limW = (NROWS - r0) * 128;
        const float* srw = aw + (size_t)r0 * 128;
        const int i = tid * 4;
        if (i < 1024) {
            float4 v = (i < limW) ? *(const float4*)(srw + i) : make_float4(0,0,0,0);
            *(float4*)(&sw[0][0] + i) = v;
        }
    }
    __syncthreads();

    const int rl  = tid >> 5;         // row within block
    const int l32 = tid & 31;
    const int h   = l32 >> 2;         // head
    const int c8  = l32 & 3;          // channel-octet
    const int row = r0 + rl;
    const int b   = row / LQ;

    const __hip_bfloat16* __restrict__ vb =
        vproj + (size_t)b * LV * 256 + h * 32 + c8 * 8;

    float acc[8] = {0.f,0.f,0.f,0.f,0.f,0.f,0.f,0.f};

    #pragma unroll
    for (int s0 = 0; s0 < 16; ++s0) {
        const int s = (s0 + h) & 15;          // bank-conflict swizzle (sum reorder only)
        const int j = h * 16 + s;
        // level params via uniform selects (s is per-lane)
        const int   wl  = (s < 8) ? ((s < 4) ? 100 : 50) : ((s < 12) ? 25 : 13);
        const float wlf = (float)wl;
        const int   st  = (s < 8) ? ((s < 4) ? 0 : 10000) : ((s < 12) ? 12500 : 13125);

        const float x = sxy[rl][2*j], y = sxy[rl][2*j + 1], a = sw[rl][j];
        const float x0f = floorf(x), y0f = floorf(y);
        const int   x0 = (int)x0f,   y0 = (int)y0f;
        const float wx1 = x - x0f, wx0 = 1.f - wx1;
        const float wy1 = y - y0f, wy0 = 1.f - wy1;
        const float w00 = a*wx0*wy0, w10 = a*wx1*wy0;
        const float w01 = a*wx0*wy1, w11 = a*wx1*wy1;
        const bool xv0 = (x0 >= 0)     && (x0     < wl);
        const bool xv1 = (x0 + 1 >= 0) && (x0 + 1 < wl);
        const bool yv0 = (y0 >= 0)     && (y0     < wl);
        const bool yv1 = (y0 + 1 >= 0) && (y0 + 1 < wl);

        const uint4 z = make_uint4(0,0,0,0);
        const size_t base = (size_t)(st + y0 * wl + x0) * 256;
        uint4 q00 = (xv0 && yv0) ? *(const uint4*)(vb + base)              : z;
        uint4 q10 = (xv1 && yv0) ? *(const uint4*)(vb + base + 256)        : z;
        uint4 q01 = (xv0 && yv1) ? *(const uint4*)(vb + base + wl * 256)   : z;
        uint4 q11 = (xv1 && yv1) ? *(const uint4*)(vb + base + wl * 256 + 256) : z;
        fma8(acc, q00, w00); fma8(acc, q10, w10);
        fma8(acc, q01, w01); fma8(acc, q11, w11);
    }

    if (row < NROWS) {
        union { ushort us[8]; uint4 v; } o;
        #pragma unroll
        for (int i = 0; i < 8; ++i)
            o.us[i] = (ushort)f2bfbits(acc[i]);
        *(uint4*)(sampled + (size_t)row * 256 + h * 32 + c8 * 8) = o.v;
    }
}

extern "C" void kernel_launch(void* const* d_in, const int* in_sizes, int n_in,
                              void* d_out, int out_size, void* d_ws, size_t ws_size,
                              hipStream_t stream)
{
    const float* query  = (const float*)d_in[0];
    const float* refpts = (const float*)d_in[1];
    const float* value  = (const float*)d_in[2];
    const float* Woff   = (const float*)d_in[4];
    const float* boff   = (const float*)d_in[5];
    const float* Wattn  = (const float*)d_in[6];
    const float* battn  = (const float*)d_in[7];
    const float* Wv     = (const float*)d_in[8];
    const float* bv     = (const float*)d_in[9];
    const float* Wout   = (const float*)d_in[10];
    const float* bout   = (const float*)d_in[11];
    float* out = (float*)d_out;

    // workspace layout (68.2 MB)
    __hip_bfloat16* vproj   = (__hip_bfloat16*)d_ws;              // NROWS*256 bf16
    __hip_bfloat16* sampled = vproj + (size_t)NROWS * 256;        // NROWS*256 bf16
    float* sloc = (float*)(sampled + (size_t)NROWS * 256);        // NROWS*256 f32
    float* aw   = sloc + (size_t)NROWS * 256;                     // NROWS*128 f32
    __hip_bfloat16* WT = (__hip_bfloat16*)(aw + (size_t)NROWS * 128); // 256*256 bf16

    const int gblk = (NROWS + 15) / 16;   // 1662
    const int sblk = (NROWS + 7) / 8;     // 3324

    hipLaunchKernelGGL(transpose_w, dim3(256), dim3(256), 0, stream, Wv, WT);
    hipLaunchKernelGGL((gemm_mfma<true, true>), dim3(gblk), dim3(256), 0, stream,
                       (const void*)value, WT, bv, (void*)vproj, NROWS);
    hipLaunchKernelGGL(off_attn_loc, dim3(sblk), dim3(256), 0, stream,
                       query, refpts, Woff, boff, Wattn, battn, sloc, aw);
    hipLaunchKernelGGL(ms_sample, dim3(sblk), dim3(256), 0, stream,
                       vproj, sloc, aw, sampled);
    hipLaunchKernelGGL(transpose_w, dim3(256), dim3(256), 0, stream, Wout, WT);
    hipLaunchKernelGGL((gemm_mfma<false, false>), dim3(gblk), dim3(256), 0, stream,
                       (const void*)sampled, WT, bout, (void*)out, NROWS);
}

// Round 3
// 391.602 us; speedup vs baseline: 1.0916x; 1.0916x over previous
//
#include <hip/hip_runtime.h>
#include <hip/hip_bf16.h>
#include <math.h>

// Deformable DETR multi-scale deformable attention — MI355X (gfx950)
// B=2, Lq=Lv=13294, D=256, H=8, HD=32, L=4, P=4
// Levels (square): 100,50,25,13  starts {0,10000,12500,13125}

namespace {
constexpr int LQ    = 13294;
constexpr int LV    = 13294;
constexpr int NROWS = 2 * LQ;   // 26588
}

typedef __attribute__((ext_vector_type(8))) short short8;   // 8 x bf16
typedef __attribute__((ext_vector_type(4))) float f32x4;    // MFMA accumulator

__device__ inline float bf2f(unsigned u16) {
    union { unsigned u; float f; } c; c.u = u16 << 16; return c.f;
}
__device__ inline unsigned short f2bf(float f) {
    __hip_bfloat16 h = __float2bfloat16(f);
    return *reinterpret_cast<unsigned short*>(&h);
}

// ---------------------------------------------------------------------------
// Weight prep: WT[896][256] bf16 = [Wv^T | Woff^T | Wattn^T | Wout^T]
// ---------------------------------------------------------------------------
__global__ __launch_bounds__(256) void prep_weights(
    const float* __restrict__ Wv, const float* __restrict__ Woff,
    const float* __restrict__ Wattn, const float* __restrict__ Wout,
    __hip_bfloat16* __restrict__ WT)
{
    const int c = blockIdx.x, k = threadIdx.x;
    float v;
    if (c < 256)      v = Wv[k * 256 + c];
    else if (c < 512) v = Woff[k * 256 + (c - 256)];
    else if (c < 640) v = Wattn[k * 128 + (c - 512)];
    else              v = Wout[k * 256 + (c - 640)];
    WT[(size_t)c * 256 + k] = __float2bfloat16(v);
}

// ---------------------------------------------------------------------------
// value + query fp32 -> bf16 (8 elems/thread)
// ---------------------------------------------------------------------------
__global__ __launch_bounds__(256) void conv_bf16(
    const float* __restrict__ value, const float* __restrict__ query,
    __hip_bfloat16* __restrict__ vbf, __hip_bfloat16* __restrict__ qbf)
{
    const size_t NV = (size_t)NROWS * 256;
    size_t e = ((size_t)blockIdx.x * 256 + threadIdx.x) * 8;
    const float* src;
    __hip_bfloat16* dst;
    if (e < NV) { src = value + e;        dst = vbf + e; }
    else        { src = query + (e - NV); dst = qbf + (e - NV); }
    const float4 a = *(const float4*)src;
    const float4 b = *(const float4*)(src + 4);
    union { unsigned short us[8]; uint4 v; } o;
    o.us[0] = f2bf(a.x); o.us[1] = f2bf(a.y); o.us[2] = f2bf(a.z); o.us[3] = f2bf(a.w);
    o.us[4] = f2bf(b.x); o.us[5] = f2bf(b.y); o.us[6] = f2bf(b.z); o.us[7] = f2bf(b.w);
    *(uint4*)dst = o.v;
}

// ---------------------------------------------------------------------------
// MFMA GEMM: Y[M][N] = X[M][256] @ W[256][N] + bias,  X bf16, WT bf16 [N][256]
// 32 rows/block (2 row-tiles), 4 waves each owning N/4 cols.
// OUTMODE 0: fp32 row-major stride 256
//         1: bf16 row-major stride N
//         2: bf16 head-major vhm[(b*8+h)*LV + lv][32]
// ---------------------------------------------------------------------------
template<int N, int OUTMODE>
__global__ __launch_bounds__(256) void gemm_mfma(
    const __hip_bfloat16* __restrict__ X, const __hip_bfloat16* __restrict__ WT,
    const float* __restrict__ biasA, const float* __restrict__ biasB, int bsplit,
    void* __restrict__ Yv, int M)
{
    constexpr int NT = N / 64;
    const int lane = threadIdx.x & 63;
    const int wv   = threadIdx.x >> 6;
    const int r0   = blockIdx.x * 32;
    const int r16  = lane & 15;
    const int koff = (lane >> 4) * 8;
    int rowA0 = r0 + r16;      if (rowA0 >= M) rowA0 = M - 1;
    int rowA1 = r0 + 16 + r16; if (rowA1 >= M) rowA1 = M - 1;

    f32x4 acc[2][NT];
    #pragma unroll
    for (int rt = 0; rt < 2; ++rt)
        #pragma unroll
        for (int nt = 0; nt < NT; ++nt)
            #pragma unroll
            for (int j = 0; j < 4; ++j) acc[rt][nt][j] = 0.f;

    #pragma unroll
    for (int kc = 0; kc < 8; ++kc) {
        const short8 a0 = *(const short8*)(X + (size_t)rowA0 * 256 + kc * 32 + koff);
        const short8 a1 = *(const short8*)(X + (size_t)rowA1 * 256 + kc * 32 + koff);
        #pragma unroll
        for (int nt = 0; nt < NT; ++nt) {
            const int col = wv * (NT * 16) + nt * 16 + r16;
            const short8 bfr = *(const short8*)(WT + (size_t)col * 256 + kc * 32 + koff);
            acc[0][nt] = __builtin_amdgcn_mfma_f32_16x16x32_bf16(a0, bfr, acc[0][nt], 0, 0, 0);
            acc[1][nt] = __builtin_amdgcn_mfma_f32_16x16x32_bf16(a1, bfr, acc[1][nt], 0, 0, 0);
        }
    }

    const int orow = (lane >> 4) * 4;
    #pragma unroll
    for (int rt = 0; rt < 2; ++rt)
    #pragma unroll
    for (int nt = 0; nt < NT; ++nt) {
        const int col = wv * (NT * 16) + nt * 16 + r16;
        const float bb = (col < bsplit) ? biasA[col] : biasB[col - bsplit];
        #pragma unroll
        for (int j = 0; j < 4; ++j) {
            const int rr = r0 + rt * 16 + orow + j;
            if (rr < M) {
                const float v = acc[rt][nt][j] + bb;
                if (OUTMODE == 0) {
                    ((float*)Yv)[(size_t)rr * 256 + col] = v;
                } else if (OUTMODE == 1) {
                    ((__hip_bfloat16*)Yv)[(size_t)rr * N + col] = __float2bfloat16(v);
                } else {
                    const int b  = (rr >= LQ) ? 1 : 0;
                    const int lv = rr - b * LQ;
                    const int h  = col >> 5, cc = col & 31;
                    ((__hip_bfloat16*)Yv)[(((size_t)(b * 8 + h)) * LV + lv) * 32 + cc] =
                        __float2bfloat16(v);
                }
            }
        }
    }
}

// ---------------------------------------------------------------------------
// Fused softmax + coords + bilinear sampling. One wave per query row.
// lane = sh*32 + h*4 + c8 : sh = sample-half (levels 2sh,2sh+1), c8 = 8 channels.
// No LDS, no barriers.
// ---------------------------------------------------------------------------
__device__ inline void fma8p(float2* acc, uint4 q, float w) {
    const unsigned u[4] = {q.x, q.y, q.z, q.w};
    #pragma unroll
    for (int i = 0; i < 4; ++i) {
        const float lo = bf2f(u[i] & 0xffffu);
        union { unsigned uu; float f; } hv; hv.uu = u[i] & 0xffff0000u;
        acc[i].x = fmaf(lo, w, acc[i].x);
        acc[i].y = fmaf(hv.f, w, acc[i].y);
    }
}

__global__ __launch_bounds__(256) void ms_sample(
    const __hip_bfloat16* __restrict__ vhm, const __hip_bfloat16* __restrict__ offlog,
    const float* __restrict__ refpts, __hip_bfloat16* __restrict__ sampled)
{
    const int lane = threadIdx.x & 63;
    const int row  = blockIdx.x * 4 + (threadIdx.x >> 6);
    const int sh   = lane >> 5;
    const int h    = (lane >> 2) & 7;
    const int c8   = lane & 3;
    const int b    = (row >= LQ) ? 1 : 0;

    const __hip_bfloat16* op = offlog + (size_t)row * 384;
    const uint4 ow0 = *(const uint4*)(op + h * 32 + sh * 16);       // samples k=0..3 (ox,oy)
    const uint4 ow1 = *(const uint4*)(op + h * 32 + sh * 16 + 8);   // samples k=4..7
    const uint4 lw  = *(const uint4*)(op + 256 + h * 16 + sh * 8);  // 8 logits
    const float4 rf = *(const float4*)(refpts + (size_t)row * 8 + sh * 4); // rx0,ry0,rx1,ry1

    // softmax over 16 (8 local + partner half via shfl_xor 32)
    float lg[8];
    {
        const unsigned u[4] = {lw.x, lw.y, lw.z, lw.w};
        #pragma unroll
        for (int i = 0; i < 4; ++i) {
            lg[2 * i]     = bf2f(u[i] & 0xffffu);
            lg[2 * i + 1] = bf2f(u[i] >> 16);
        }
    }
    float m = lg[0];
    #pragma unroll
    for (int k = 1; k < 8; ++k) m = fmaxf(m, lg[k]);
    m = fmaxf(m, __shfl_xor(m, 32));
    float aw[8], s = 0.f;
    #pragma unroll
    for (int k = 0; k < 8; ++k) { aw[k] = __expf(lg[k] - m); s += aw[k]; }
    s += __shfl_xor(s, 32);
    const float inv = 1.0f / s;
    #pragma unroll
    for (int k = 0; k < 8; ++k) aw[k] *= inv;

    float ox[8], oy[8];
    {
        const unsigned u0[4] = {ow0.x, ow0.y, ow0.z, ow0.w};
        const unsigned u1[4] = {ow1.x, ow1.y, ow1.z, ow1.w};
        #pragma unroll
        for (int i = 0; i < 4; ++i) {
            ox[i]     = bf2f(u0[i] & 0xffffu); oy[i]     = bf2f(u0[i] >> 16);
            ox[4 + i] = bf2f(u1[i] & 0xffffu); oy[4 + i] = bf2f(u1[i] >> 16);
        }
    }

    float2 acc[4] = {{0.f,0.f},{0.f,0.f},{0.f,0.f},{0.f,0.f}};

    #pragma unroll
    for (int li = 0; li < 2; ++li) {
        const int wl = sh ? (li ? 13 : 25) : (li ? 50 : 100);
        const int st = sh ? (li ? 13125 : 12500) : (li ? 10000 : 0);
        const float wlf = (float)wl;
        const int wstep = wl * 32;
        const __hip_bfloat16* vb = vhm + ((size_t)((b << 3) + h) * LV + st) * 32 + c8 * 8;
        const float bx = (li ? rf.z : rf.x) * wlf - 0.5f;
        const float by = (li ? rf.w : rf.y) * wlf - 0.5f;
        #pragma unroll
        for (int p = 0; p < 4; ++p) {
            const int k = li * 4 + p;
            const float x = bx + ox[k], y = by + oy[k];
            const float x0f = floorf(x), y0f = floorf(y);
            const int x0 = (int)x0f, y0 = (int)y0f;
            const float wx1 = x - x0f, wy1 = y - y0f;
            const float wx0 = 1.f - wx1, wy0 = 1.f - wy1;
            const float a = aw[k];
            const float ax0 = a * wx0, ax1 = a * wx1;
            const float w00 = ax0 * wy0, w10 = ax1 * wy0;
            const float w01 = ax0 * wy1, w11 = ax1 * wy1;
            const bool xv0 = (unsigned)x0 < (unsigned)wl;
            const bool xv1 = (unsigned)(x0 + 1) < (unsigned)wl;
            const bool yv0 = (unsigned)y0 < (unsigned)wl;
            const bool yv1 = (unsigned)(y0 + 1) < (unsigned)wl;
            const __hip_bfloat16* pp = vb + ((ptrdiff_t)y0 * wl + x0) * 32;
            const uint4 z = make_uint4(0, 0, 0, 0);
            const uint4 q00 = (xv0 && yv0) ? *(const uint4*)(pp)              : z;
            const uint4 q10 = (xv1 && yv0) ? *(const uint4*)(pp + 32)         : z;
            const uint4 q01 = (xv0 && yv1) ? *(const uint4*)(pp + wstep)      : z;
            const uint4 q11 = (xv1 && yv1) ? *(const uint4*)(pp + wstep + 32) : z;
            fma8p(acc, q00, w00); fma8p(acc, q10, w10);
            fma8p(acc, q01, w01); fma8p(acc, q11, w11);
        }
    }

    #pragma unroll
    for (int i = 0; i < 4; ++i) {
        acc[i].x += __shfl_xor(acc[i].x, 32);
        acc[i].y += __shfl_xor(acc[i].y, 32);
    }
    if (sh == 0) {
        union { unsigned short us[8]; uint4 v; } o;
        #pragma unroll
        for (int i = 0; i < 4; ++i) {
            o.us[2 * i]     = f2bf(acc[i].x);
            o.us[2 * i + 1] = f2bf(acc[i].y);
        }
        *(uint4*)(sampled + (size_t)row * 256 + h * 32 + c8 * 8) = o.v;
    }
}

extern "C" void kernel_launch(void* const* d_in, const int* in_sizes, int n_in,
                              void* d_out, int out_size, void* d_ws, size_t ws_size,
                              hipStream_t stream)
{
    const float* query  = (const float*)d_in[0];
    const float* refpts = (const float*)d_in[1];
    const float* value  = (const float*)d_in[2];
    const float* Woff   = (const float*)d_in[4];
    const float* boff   = (const float*)d_in[5];
    const float* Wattn  = (const float*)d_in[6];
    const float* battn  = (const float*)d_in[7];
    const float* Wv     = (const float*)d_in[8];
    const float* bv     = (const float*)d_in[9];
    const float* Wout   = (const float*)d_in[10];
    const float* bout   = (const float*)d_in[11];
    float* out = (float*)d_out;

    // workspace (bf16 elements): 61.7 MB total
    constexpr size_t SZ_VHM = (size_t)2 * 8 * LV * 32;      // 6,806,528
    constexpr size_t SZ_OFF = (size_t)NROWS * 384;          // 10,209,792
    constexpr size_t SZ_ROW = (size_t)NROWS * 256;          // 6,806,528
    __hip_bfloat16* ws     = (__hip_bfloat16*)d_ws;
    __hip_bfloat16* vhm    = ws;
    __hip_bfloat16* offlog = vhm + SZ_VHM;
    __hip_bfloat16* vbf    = offlog + SZ_OFF;   // reused as `sampled` after gemm_v
    __hip_bfloat16* qbf    = vbf + SZ_ROW;
    __hip_bfloat16* WT     = qbf + SZ_ROW;      // 896*256

    const int gblk = (NROWS + 31) / 32;   // 831
    const int cblk = NROWS / 4;           // 6647 (exact: NROWS*512/2048)

    hipLaunchKernelGGL(prep_weights, dim3(896), dim3(256), 0, stream,
                       Wv, Woff, Wattn, Wout, WT);
    hipLaunchKernelGGL(conv_bf16, dim3(cblk), dim3(256), 0, stream,
                       value, query, vbf, qbf);
    hipLaunchKernelGGL((gemm_mfma<256, 2>), dim3(gblk), dim3(256), 0, stream,
                       vbf, WT, bv, bv, 256, (void*)vhm, NROWS);
    hipLaunchKernelGGL((gemm_mfma<384, 1>), dim3(gblk), dim3(256), 0, stream,
                       qbf, WT + 256 * 256, boff, battn, 256, (void*)offlog, NROWS);
    hipLaunchKernelGGL(ms_sample, dim3(cblk), dim3(256), 0, stream,
                       vhm, offlog, refpts, vbf /* sampled */);
    hipLaunchKernelGGL((gemm_mfma<256, 0>), dim3(gblk), dim3(256), 0, stream,
                       vbf, WT + 640 * 256, bout, bout, 256, (void*)out, NROWS);
}

// Round 4
// 177.205 us; speedup vs baseline: 2.4124x; 2.2099x over previous
//
#include <hip/hip_runtime.h>
#include <hip/hip_bf16.h>
#include <math.h>

// Deformable DETR multi-scale deformable attention — MI355X (gfx950)
// B=2, Lq=Lv=13294, D=256, H=8, HD=32, L=4, P=4
// Levels (square): 100,50,25,13  starts {0,10000,12500,13125}

namespace {
constexpr int LQ    = 13294;
constexpr int LV    = 13294;
constexpr int NROWS = 2 * LQ;   // 26588
}

typedef __attribute__((ext_vector_type(8))) short short8;   // 8 x bf16
typedef __attribute__((ext_vector_type(4))) float f32x4;    // MFMA accumulator

__device__ inline float bf2f(unsigned u16) {
    union { unsigned u; float f; } c; c.u = u16 << 16; return c.f;
}
__device__ inline unsigned short f2bf(float f) {
    __hip_bfloat16 h = __float2bfloat16(f);
    return *reinterpret_cast<unsigned short*>(&h);
}

// ---------------------------------------------------------------------------
// Weight prep: WT[896][256] bf16 = [Wv^T | Woff^T | Wattn^T | Wout^T]
// ---------------------------------------------------------------------------
__global__ __launch_bounds__(256) void prep_weights(
    const float* __restrict__ Wv, const float* __restrict__ Woff,
    const float* __restrict__ Wattn, const float* __restrict__ Wout,
    __hip_bfloat16* __restrict__ WT)
{
    const int c = blockIdx.x, k = threadIdx.x;
    float v;
    if (c < 256)      v = Wv[k * 256 + c];
    else if (c < 512) v = Woff[k * 256 + (c - 256)];
    else if (c < 640) v = Wattn[k * 128 + (c - 512)];
    else              v = Wout[k * 256 + (c - 640)];
    WT[(size_t)c * 256 + k] = __float2bfloat16(v);
}

// ---------------------------------------------------------------------------
// MFMA GEMM: Y[M][N] = X[M][256] @ W[256][N] + bias,  WT bf16 [N][256]
// A_FP32: X fp32, converted inline (each row consumed exactly once).
// 32 rows/block (2 row-tiles), 4 waves each owning N/4 cols.
// OUTMODE 0: fp32 row-major stride 256
//         1: bf16 row-major stride N
//         2: bf16 head-major vhm[(b*8+h)*LV + lv][32]
// ---------------------------------------------------------------------------
template<int N, int OUTMODE, bool A_FP32>
__global__ __launch_bounds__(256) void gemm_mfma(
    const void* __restrict__ Xv, const __hip_bfloat16* __restrict__ WT,
    const float* __restrict__ biasA, const float* __restrict__ biasB, int bsplit,
    void* __restrict__ Yv, int M)
{
    constexpr int NT = N / 64;
    const int lane = threadIdx.x & 63;
    const int wv   = threadIdx.x >> 6;
    const int r0   = blockIdx.x * 32;
    const int r16  = lane & 15;
    const int koff = (lane >> 4) * 8;
    int rowA0 = r0 + r16;      if (rowA0 >= M) rowA0 = M - 1;
    int rowA1 = r0 + 16 + r16; if (rowA1 >= M) rowA1 = M - 1;

    f32x4 acc[2][NT];
    #pragma unroll
    for (int rt = 0; rt < 2; ++rt)
        #pragma unroll
        for (int nt = 0; nt < NT; ++nt)
            #pragma unroll
            for (int j = 0; j < 4; ++j) acc[rt][nt][j] = 0.f;

    #pragma unroll
    for (int kc = 0; kc < 8; ++kc) {
        short8 a0, a1;
        if (A_FP32) {
            const float* p0 = (const float*)Xv + (size_t)rowA0 * 256 + kc * 32 + koff;
            const float* p1 = (const float*)Xv + (size_t)rowA1 * 256 + kc * 32 + koff;
            const float4 u0 = *(const float4*)p0, u1 = *(const float4*)(p0 + 4);
            const float4 v0 = *(const float4*)p1, v1 = *(const float4*)(p1 + 4);
            a0[0]=f2bf(u0.x); a0[1]=f2bf(u0.y); a0[2]=f2bf(u0.z); a0[3]=f2bf(u0.w);
            a0[4]=f2bf(u1.x); a0[5]=f2bf(u1.y); a0[6]=f2bf(u1.z); a0[7]=f2bf(u1.w);
            a1[0]=f2bf(v0.x); a1[1]=f2bf(v0.y); a1[2]=f2bf(v0.z); a1[3]=f2bf(v0.w);
            a1[4]=f2bf(v1.x); a1[5]=f2bf(v1.y); a1[6]=f2bf(v1.z); a1[7]=f2bf(v1.w);
        } else {
            a0 = *(const short8*)((const __hip_bfloat16*)Xv + (size_t)rowA0 * 256 + kc * 32 + koff);
            a1 = *(const short8*)((const __hip_bfloat16*)Xv + (size_t)rowA1 * 256 + kc * 32 + koff);
        }
        #pragma unroll
        for (int nt = 0; nt < NT; ++nt) {
            const int col = wv * (NT * 16) + nt * 16 + r16;
            const short8 bfr = *(const short8*)(WT + (size_t)col * 256 + kc * 32 + koff);
            acc[0][nt] = __builtin_amdgcn_mfma_f32_16x16x32_bf16(a0, bfr, acc[0][nt], 0, 0, 0);
            acc[1][nt] = __builtin_amdgcn_mfma_f32_16x16x32_bf16(a1, bfr, acc[1][nt], 0, 0, 0);
        }
    }

    const int orow = (lane >> 4) * 4;
    #pragma unroll
    for (int rt = 0; rt < 2; ++rt)
    #pragma unroll
    for (int nt = 0; nt < NT; ++nt) {
        const int col = wv * (NT * 16) + nt * 16 + r16;
        const float bb = (col < bsplit) ? biasA[col] : biasB[col - bsplit];
        #pragma unroll
        for (int j = 0; j < 4; ++j) {
            const int rr = r0 + rt * 16 + orow + j;
            if (rr < M) {
                const float v = acc[rt][nt][j] + bb;
                if (OUTMODE == 0) {
                    ((float*)Yv)[(size_t)rr * 256 + col] = v;
                } else if (OUTMODE == 1) {
                    ((__hip_bfloat16*)Yv)[(size_t)rr * N + col] = __float2bfloat16(v);
                } else {
                    const int b  = (rr >= LQ) ? 1 : 0;
                    const int lv = rr - b * LQ;
                    const int h  = col >> 5, cc = col & 31;
                    ((__hip_bfloat16*)Yv)[(((size_t)(b * 8 + h)) * LV + lv) * 32 + cc] =
                        __float2bfloat16(v);
                }
            }
        }
    }
}

// ---------------------------------------------------------------------------
// ms_sample v4: two-phase, 2 rows per 256-thread block.
// Phase 1: thread (rl, h, s) computes one param set: 4 clamped corner byte
//   offsets + 4 bilinear weights (premultiplied by softmax attention, zeroed
//   when the corner is out of bounds). -> LDS, padded stride (broadcast reads).
// Phase 2: thread (rl, h, c2) owns 2 bf16 channels; per sample: 2 broadcast
//   ds_read_b128 + 4 unconditional 4B gathers (16 lanes x 4B = 64B contiguous
//   per head) + unpack/FMA.
// ---------------------------------------------------------------------------
__global__ __launch_bounds__(256) void ms_sample(
    const __hip_bfloat16* __restrict__ vhm, const __hip_bfloat16* __restrict__ offlog,
    const float* __restrict__ refpts, __hip_bfloat16* __restrict__ sampled)
{
    // [rl][s][h*32B], s-stride padded to 288B => conflict-free phase-2 reads
    __shared__ char params[2][16][288];

    const int t   = threadIdx.x;
    const int rl  = t >> 7;
    const int h   = (t >> 4) & 7;
    const int row = blockIdx.x * 2 + rl;
    const int b   = (row >= LQ) ? 1 : 0;

    // ---------------- phase 1 ----------------
    {
        const int s = t & 15;
        const int l = s >> 2;
        const int wl = (l == 0) ? 100 : (l == 1) ? 50 : (l == 2) ? 25 : 13;
        const int st = (l == 0) ? 0 : (l == 1) ? 10000 : (l == 2) ? 12500 : 13125;
        const float wlf = (float)wl;

        const unsigned short* ol = (const unsigned short*)offlog + (size_t)row * 384;
        const unsigned uoff = *(const unsigned*)(ol + h * 32 + s * 2);
        const float ox = bf2f(uoff & 0xffffu), oy = bf2f(uoff >> 16);
        const float lg = bf2f(ol[256 + h * 16 + s]);
        const float2 rf = *(const float2*)(refpts + (size_t)row * 8 + l * 2);

        // softmax over the 16 lanes of this (row, h)
        float m = lg;
        #pragma unroll
        for (int o = 8; o > 0; o >>= 1) m = fmaxf(m, __shfl_xor(m, o, 16));
        const float e = __expf(lg - m);
        float ssum = e;
        #pragma unroll
        for (int o = 8; o > 0; o >>= 1) ssum += __shfl_xor(ssum, o, 16);
        const float a = e / ssum;

        const float x = fmaf(rf.x, wlf, ox) - 0.5f;
        const float y = fmaf(rf.y, wlf, oy) - 0.5f;
        const float x0f = floorf(x), y0f = floorf(y);
        const int   x0 = (int)x0f, y0 = (int)y0f;
        const float wx1 = x - x0f, wx0 = 1.f - wx1;
        const float wy1 = y - y0f, wy0 = 1.f - wy1;
        const bool xv0 = (unsigned)x0       < (unsigned)wl;
        const bool xv1 = (unsigned)(x0 + 1) < (unsigned)wl;
        const bool yv0 = (unsigned)y0       < (unsigned)wl;
        const bool yv1 = (unsigned)(y0 + 1) < (unsigned)wl;
        const float ax0 = a * wx0, ax1 = a * wx1;
        float w00 = ax0 * wy0, w10 = ax1 * wy0;
        float w01 = ax0 * wy1, w11 = ax1 * wy1;
        w00 = (xv0 && yv0) ? w00 : 0.f;
        w10 = (xv1 && yv0) ? w10 : 0.f;
        w01 = (xv0 && yv1) ? w01 : 0.f;
        w11 = (xv1 && yv1) ? w11 : 0.f;
        const int cx0 = min(max(x0, 0), wl - 1);
        const int cx1 = min(max(x0 + 1, 0), wl - 1);
        const int cy0 = min(max(y0, 0), wl - 1);
        const int cy1 = min(max(y0 + 1, 0), wl - 1);
        const int r0b = (st + cy0 * wl) * 64;   // byte offsets into head plane
        const int r1b = (st + cy1 * wl) * 64;
        uint4  offs; offs.x = r0b + cx0 * 64; offs.y = r0b + cx1 * 64;
                     offs.z = r1b + cx0 * 64; offs.w = r1b + cx1 * 64;
        float4 wv4;  wv4.x = w00; wv4.y = w10; wv4.z = w01; wv4.w = w11;
        char* pe = &params[rl][s][h * 32];
        *(uint4*)pe        = offs;
        *(float4*)(pe + 16) = wv4;
    }
    __syncthreads();

    // ---------------- phase 2 ----------------
    const int c2 = t & 15;
    const char* vbase = (const char*)vhm + ((size_t)((b << 3) + h) * LV) * 64 + c2 * 4;

    float ax = 0.f, ay = 0.f;
    #pragma unroll
    for (int s = 0; s < 16; ++s) {
        const char* pe = &params[rl][s][h * 32];
        const uint4  offs = *(const uint4*)pe;
        const float4 w    = *(const float4*)(pe + 16);
        const unsigned u00 = *(const unsigned*)(vbase + offs.x);
        const unsigned u10 = *(const unsigned*)(vbase + offs.y);
        const unsigned u01 = *(const unsigned*)(vbase + offs.z);
        const unsigned u11 = *(const unsigned*)(vbase + offs.w);
        union { unsigned u; float f; } lo, hi;
        lo.u = u00 << 16;          ax = fmaf(lo.f, w.x, ax);
        hi.u = u00 & 0xffff0000u;  ay = fmaf(hi.f, w.x, ay);
        lo.u = u10 << 16;          ax = fmaf(lo.f, w.y, ax);
        hi.u = u10 & 0xffff0000u;  ay = fmaf(hi.f, w.y, ay);
        lo.u = u01 << 16;          ax = fmaf(lo.f, w.z, ax);
        hi.u = u01 & 0xffff0000u;  ay = fmaf(hi.f, w.z, ay);
        lo.u = u11 << 16;          ax = fmaf(lo.f, w.w, ax);
        hi.u = u11 & 0xffff0000u;  ay = fmaf(hi.f, w.w, ay);
    }

    const unsigned o = (unsigned)f2bf(ax) | ((unsigned)f2bf(ay) << 16);
    *(unsigned*)((unsigned short*)sampled + (size_t)row * 256 + h * 32 + c2 * 2) = o;
}

extern "C" void kernel_launch(void* const* d_in, const int* in_sizes, int n_in,
                              void* d_out, int out_size, void* d_ws, size_t ws_size,
                              hipStream_t stream)
{
    const float* query  = (const float*)d_in[0];
    const float* refpts = (const float*)d_in[1];
    const float* value  = (const float*)d_in[2];
    const float* Woff   = (const float*)d_in[4];
    const float* boff   = (const float*)d_in[5];
    const float* Wattn  = (const float*)d_in[6];
    const float* battn  = (const float*)d_in[7];
    const float* Wv     = (const float*)d_in[8];
    const float* bv     = (const float*)d_in[9];
    const float* Wout   = (const float*)d_in[10];
    const float* bout   = (const float*)d_in[11];
    float* out = (float*)d_out;

    // workspace (bf16 elements): 48.1 MB total
    constexpr size_t SZ_VHM = (size_t)2 * 8 * LV * 32;      // 6,806,528
    constexpr size_t SZ_OFF = (size_t)NROWS * 384;          // 10,209,792
    constexpr size_t SZ_ROW = (size_t)NROWS * 256;          // 6,806,528
    __hip_bfloat16* ws      = (__hip_bfloat16*)d_ws;
    __hip_bfloat16* vhm     = ws;
    __hip_bfloat16* offlog  = vhm + SZ_VHM;
    __hip_bfloat16* sampled = offlog + SZ_OFF;
    __hip_bfloat16* WT      = sampled + SZ_ROW;             // 896*256

    const int gblk = (NROWS + 31) / 32;   // 831
    const int sblk = NROWS / 2;           // 13294

    hipLaunchKernelGGL(prep_weights, dim3(896), dim3(256), 0, stream,
                       Wv, Woff, Wattn, Wout, WT);
    hipLaunchKernelGGL((gemm_mfma<256, 2, true>), dim3(gblk), dim3(256), 0, stream,
                       (const void*)value, WT, bv, bv, 256, (void*)vhm, NROWS);
    hipLaunchKernelGGL((gemm_mfma<384, 1, true>), dim3(gblk), dim3(256), 0, stream,
                       (const void*)query, WT + 256 * 256, boff, battn, 256,
                       (void*)offlog, NROWS);
    hipLaunchKernelGGL(ms_sample, dim3(sblk), dim3(256), 0, stream,
                       vhm, offlog, refpts, sampled);
    hipLaunchKernelGGL((gemm_mfma<256, 0, false>), dim3(gblk), dim3(256), 0, stream,
                       (const void*)sampled, WT + 640 * 256, bout, bout, 256,
                       (void*)out, NROWS);
}

// Round 5
// 145.492 us; speedup vs baseline: 2.9382x; 1.2180x over previous
//
#include <hip/hip_runtime.h>
#include <hip/hip_bf16.h>
#include <math.h>

// Deformable DETR multi-scale deformable attention — MI355X (gfx950)
// B=2, Lq=Lv=13294, D=256, H=8, HD=32, L=4, P=4
// Levels (square): 100,50,25,13  starts {0,10000,12500,13125}

namespace {
constexpr int LQ    = 13294;
constexpr int LV    = 13294;
constexpr int NROWS = 2 * LQ;   // 26588
}

typedef __attribute__((ext_vector_type(8))) short short8;   // 8 x bf16
typedef __attribute__((ext_vector_type(4))) float f32x4;    // MFMA accumulator

__device__ inline float bf2f(unsigned u16) {
    union { unsigned u; float f; } c; c.u = u16 << 16; return c.f;
}
__device__ inline unsigned short f2bf(float f) {
    __hip_bfloat16 h = __float2bfloat16(f);
    return *reinterpret_cast<unsigned short*>(&h);
}

// ---------------------------------------------------------------------------
// Weight prep via LDS tile transpose (coalesced read + write):
// WT[896][256] bf16 = [Wv^T | Woff^T | Wattn^T | Wout^T]
// grid (14 c-tiles, 4 k-tiles), 64x64 tile.
// ---------------------------------------------------------------------------
__global__ __launch_bounds__(256) void prep_weights(
    const float* __restrict__ Wv, const float* __restrict__ Woff,
    const float* __restrict__ Wattn, const float* __restrict__ Wout,
    __hip_bfloat16* __restrict__ WT)
{
    __shared__ float tile[64][65];
    const int c0 = blockIdx.x * 64;
    const int k0 = blockIdx.y * 64;
    const float* src; int width, coff;
    if (c0 < 256)      { src = Wv;    width = 256; coff = 0; }
    else if (c0 < 512) { src = Woff;  width = 256; coff = 256; }
    else if (c0 < 640) { src = Wattn; width = 128; coff = 512; }
    else               { src = Wout;  width = 256; coff = 640; }
    const int t = threadIdx.x;
    #pragma unroll
    for (int i = 0; i < 16; ++i) {
        const int idx = i * 256 + t;
        const int kr = idx >> 6, cc = idx & 63;
        tile[kr][cc] = src[(size_t)(k0 + kr) * width + (c0 - coff) + cc];
    }
    __syncthreads();
    #pragma unroll
    for (int i = 0; i < 16; ++i) {
        const int idx = i * 256 + t;
        const int cr = idx >> 6, kk = idx & 63;
        WT[(size_t)(c0 + cr) * 256 + k0 + kk] = __float2bfloat16(tile[kk][cr]);
    }
}

// ---------------------------------------------------------------------------
// GEMM cores: Y[M][N] = X[M][256] @ W[256][N] + bias, WT bf16 [N][256].
// A staged through LDS (coalesced global load, bf16 in LDS, ds_read_b128
// fragments shared by all 4 waves). 32 rows/block, wave owns N/4 cols.
// OUTMODE 0: fp32 row-major 256 | 1: bf16 row-major N | 2: bf16 head-major
// ---------------------------------------------------------------------------
template<int N, int OUTMODE>
__device__ __forceinline__ void gemm_epilogue(
    f32x4 (&acc)[2][N / 64], const float* biasA, const float* biasB, int bsplit,
    void* Yv, int M, int r0, int lane, int wv)
{
    constexpr int NT = N / 64;
    const int r16  = lane & 15;
    const int orow = (lane >> 4) * 4;
    #pragma unroll
    for (int rt = 0; rt < 2; ++rt)
    #pragma unroll
    for (int nt = 0; nt < NT; ++nt) {
        const int col = wv * (NT * 16) + nt * 16 + r16;
        const float bb = (col < bsplit) ? biasA[col] : biasB[col - bsplit];
        #pragma unroll
        for (int j = 0; j < 4; ++j) {
            const int rr = r0 + rt * 16 + orow + j;
            if (rr < M) {
                const float v = acc[rt][nt][j] + bb;
                if (OUTMODE == 0) {
                    ((float*)Yv)[(size_t)rr * 256 + col] = v;
                } else if (OUTMODE == 1) {
                    ((__hip_bfloat16*)Yv)[(size_t)rr * N + col] = __float2bfloat16(v);
                } else {
                    const int b  = (rr >= LQ) ? 1 : 0;
                    const int lv = rr - b * LQ;
                    const int h  = col >> 5, cc = col & 31;
                    ((__hip_bfloat16*)Yv)[(((size_t)(b * 8 + h)) * LV + lv) * 32 + cc] =
                        __float2bfloat16(v);
                }
            }
        }
    }
}

template<int N, int OUTMODE, bool A_FP32>
__device__ __forceinline__ void gemm_core(
    short (*As)[264], const void* __restrict__ Xv,
    const __hip_bfloat16* __restrict__ WT,
    const float* __restrict__ biasA, const float* __restrict__ biasB, int bsplit,
    void* __restrict__ Yv, int M, int bx)
{
    constexpr int NT = N / 64;
    const int t  = threadIdx.x;
    const int r0 = bx * 32;

    // ---- stage A (32 rows x 256) into LDS as bf16, coalesced ----
    if (A_FP32) {
        const float* X = (const float*)Xv;
        #pragma unroll
        for (int i = 0; i < 8; ++i) {
            const int f4 = i * 256 + t;          // 2048 float4s
            int row = r0 + (f4 >> 6);
            if (row >= M) row = M - 1;
            const int col4 = f4 & 63;
            const float4 u = *(const float4*)(X + (size_t)row * 256 + col4 * 4);
            union { unsigned short us[4]; uint2 v; } p;
            p.us[0] = f2bf(u.x); p.us[1] = f2bf(u.y);
            p.us[2] = f2bf(u.z); p.us[3] = f2bf(u.w);
            *(uint2*)(&As[f4 >> 6][col4 * 4]) = p.v;
        }
    } else {
        const __hip_bfloat16* X = (const __hip_bfloat16*)Xv;
        #pragma unroll
        for (int i = 0; i < 4; ++i) {
            const int f8 = i * 256 + t;          // 1024 16B-chunks
            int row = r0 + (f8 >> 5);
            if (row >= M) row = M - 1;
            const int c16 = f8 & 31;
            const short8 v = *(const short8*)(X + (size_t)row * 256 + c16 * 8);
            *(short8*)(&As[f8 >> 5][c16 * 8]) = v;
        }
    }
    __syncthreads();

    const int lane = t & 63;
    const int wv   = t >> 6;
    const int r16  = lane & 15;
    const int koff = (lane >> 4) * 8;

    f32x4 acc[2][NT];
    #pragma unroll
    for (int rt = 0; rt < 2; ++rt)
        #pragma unroll
        for (int nt = 0; nt < NT; ++nt)
            #pragma unroll
            for (int j = 0; j < 4; ++j) acc[rt][nt][j] = 0.f;

    #pragma unroll
    for (int kc = 0; kc < 8; ++kc) {
        const short8 a0 = *(const short8*)(&As[r16][kc * 32 + koff]);
        const short8 a1 = *(const short8*)(&As[16 + r16][kc * 32 + koff]);
        #pragma unroll
        for (int nt = 0; nt < NT; ++nt) {
            const int col = wv * (NT * 16) + nt * 16 + r16;
            const short8 bfr = *(const short8*)(WT + (size_t)col * 256 + kc * 32 + koff);
            acc[0][nt] = __builtin_amdgcn_mfma_f32_16x16x32_bf16(a0, bfr, acc[0][nt], 0, 0, 0);
            acc[1][nt] = __builtin_amdgcn_mfma_f32_16x16x32_bf16(a1, bfr, acc[1][nt], 0, 0, 0);
        }
    }

    gemm_epilogue<N, OUTMODE>(acc, biasA, biasB, bsplit, Yv, M, r0, lane, wv);
}

// fused value-GEMM (y==0) + query-GEMM (y==1)
__global__ __launch_bounds__(256) void gemm_vq(
    const float* __restrict__ value, const float* __restrict__ query,
    const __hip_bfloat16* __restrict__ WT,
    const float* __restrict__ bv, const float* __restrict__ boff,
    const float* __restrict__ battn,
    __hip_bfloat16* __restrict__ vhm, __hip_bfloat16* __restrict__ offlog, int M)
{
    __shared__ short As[32][264];
    if (blockIdx.y == 0)
        gemm_core<256, 2, true>(As, value, WT, bv, bv, 256, vhm, M, blockIdx.x);
    else
        gemm_core<384, 1, true>(As, query, WT + 256 * 256, boff, battn, 256,
                                offlog, M, blockIdx.x);
}

__global__ __launch_bounds__(256) void gemm_out_k(
    const __hip_bfloat16* __restrict__ sampled, const __hip_bfloat16* __restrict__ WT,
    const float* __restrict__ bout, float* __restrict__ out, int M)
{
    __shared__ short As[32][264];
    gemm_core<256, 0, false>(As, sampled, WT, bout, bout, 256, out, M, blockIdx.x);
}

// ---------------------------------------------------------------------------
// ms_sample v5: 4 rows per 256-thread block.
// Phase 1 (x2 iters): thread -> one (row, head, sample) param set: 4 clamped
//   corner byte offsets + 4 bilinear*attention weights (zeroed OOB) -> LDS.
// Phase 2: thread = (rl, h, c4) owns 4 bf16 channels; per sample: 2 broadcast
//   ds_read_b128 + 4 unconditional 8B gathers (8 lanes x 8B = 64B contiguous
//   per head-corner) + unpack/FMA.
// ---------------------------------------------------------------------------
__global__ __launch_bounds__(256) void ms_sample(
    const __hip_bfloat16* __restrict__ vhm, const __hip_bfloat16* __restrict__ offlog,
    const float* __restrict__ refpts, __hip_bfloat16* __restrict__ sampled)
{
    __shared__ char params[4][16][304];   // stride 304B: 16B-aligned, bank-spread

    const int t    = threadIdx.x;
    const int row0 = blockIdx.x * 4;

    // ---------------- phase 1 ----------------
    #pragma unroll
    for (int it = 0; it < 2; ++it) {
        const int sid = it * 256 + t;
        const int rl  = sid >> 7;
        const int h   = (sid >> 4) & 7;
        const int s   = sid & 15;
        const int row = row0 + rl;
        const int l   = s >> 2;
        const int wl  = (l == 0) ? 100 : (l == 1) ? 50 : (l == 2) ? 25 : 13;
        const int st  = (l == 0) ? 0 : (l == 1) ? 10000 : (l == 2) ? 12500 : 13125;
        const float wlf = (float)wl;

        const unsigned short* ol = (const unsigned short*)offlog + (size_t)row * 384;
        const unsigned uoff = *(const unsigned*)(ol + h * 32 + s * 2);
        const float ox = bf2f(uoff & 0xffffu), oy = bf2f(uoff >> 16);
        const float lg = bf2f(ol[256 + h * 16 + s]);
        const float2 rf = *(const float2*)(refpts + (size_t)row * 8 + l * 2);

        // softmax over the 16 lanes of this (row, h)
        float m = lg;
        #pragma unroll
        for (int o = 8; o > 0; o >>= 1) m = fmaxf(m, __shfl_xor(m, o, 16));
        const float e = __expf(lg - m);
        float ssum = e;
        #pragma unroll
        for (int o = 8; o > 0; o >>= 1) ssum += __shfl_xor(ssum, o, 16);
        const float a = e / ssum;

        const float x = fmaf(rf.x, wlf, ox) - 0.5f;
        const float y = fmaf(rf.y, wlf, oy) - 0.5f;
        const float x0f = floorf(x), y0f = floorf(y);
        const int   x0 = (int)x0f, y0 = (int)y0f;
        const float wx1 = x - x0f, wx0 = 1.f - wx1;
        const float wy1 = y - y0f, wy0 = 1.f - wy1;
        const bool xv0 = (unsigned)x0       < (unsigned)wl;
        const bool xv1 = (unsigned)(x0 + 1) < (unsigned)wl;
        const bool yv0 = (unsigned)y0       < (unsigned)wl;
        const bool yv1 = (unsigned)(y0 + 1) < (unsigned)wl;
        const float ax0 = a * wx0, ax1 = a * wx1;
        float w00 = ax0 * wy0, w10 = ax1 * wy0;
        float w01 = ax0 * wy1, w11 = ax1 * wy1;
        w00 = (xv0 && yv0) ? w00 : 0.f;
        w10 = (xv1 && yv0) ? w10 : 0.f;
        w01 = (xv0 && yv1) ? w01 : 0.f;
        w11 = (xv1 && yv1) ? w11 : 0.f;
        const int cx0 = min(max(x0, 0), wl - 1);
        const int cx1 = min(max(x0 + 1, 0), wl - 1);
        const int cy0 = min(max(y0, 0), wl - 1);
        const int cy1 = min(max(y0 + 1, 0), wl - 1);
        const int r0b = (st + cy0 * wl) * 64;   // byte offsets into head plane
        const int r1b = (st + cy1 * wl) * 64;
        uint4  offs; offs.x = r0b + cx0 * 64; offs.y = r0b + cx1 * 64;
                     offs.z = r1b + cx0 * 64; offs.w = r1b + cx1 * 64;
        float4 wv4;  wv4.x = w00; wv4.y = w10; wv4.z = w01; wv4.w = w11;
        char* pe = &params[rl][s][h * 32];
        *(uint4*)pe         = offs;
        *(float4*)(pe + 16) = wv4;
    }
    __syncthreads();

    // ---------------- phase 2 ----------------
    const int rl  = t >> 6;
    const int h   = (t >> 3) & 7;
    const int c4  = t & 7;
    const int row = row0 + rl;
    const int b   = (row >= LQ) ? 1 : 0;
    const char* vbase = (const char*)vhm + ((size_t)((b << 3) + h) * LV) * 64 + c4 * 8;

    float a0 = 0.f, a1 = 0.f, a2 = 0.f, a3 = 0.f;
    #pragma unroll
    for (int s = 0; s < 16; ++s) {
        const char* pe = &params[rl][s][h * 32];
        const uint4  offs = *(const uint4*)pe;
        const float4 w    = *(const float4*)(pe + 16);
        const uint2 q00 = *(const uint2*)(vbase + offs.x);
        const uint2 q10 = *(const uint2*)(vbase + offs.y);
        const uint2 q01 = *(const uint2*)(vbase + offs.z);
        const uint2 q11 = *(const uint2*)(vbase + offs.w);
        union { unsigned u; float f; } lo, hi;
        lo.u = q00.x << 16;          a0 = fmaf(lo.f, w.x, a0);
        hi.u = q00.x & 0xffff0000u;  a1 = fmaf(hi.f, w.x, a1);
        lo.u = q00.y << 16;          a2 = fmaf(lo.f, w.x, a2);
        hi.u = q00.y & 0xffff0000u;  a3 = fmaf(hi.f, w.x, a3);
        lo.u = q10.x << 16;          a0 = fmaf(lo.f, w.y, a0);
        hi.u = q10.x & 0xffff0000u;  a1 = fmaf(hi.f, w.y, a1);
        lo.u = q10.y << 16;          a2 = fmaf(lo.f, w.y, a2);
        hi.u = q10.y & 0xffff0000u;  a3 = fmaf(hi.f, w.y, a3);
        lo.u = q01.x << 16;          a0 = fmaf(lo.f, w.z, a0);
        hi.u = q01.x & 0xffff0000u;  a1 = fmaf(hi.f, w.z, a1);
        lo.u = q01.y << 16;          a2 = fmaf(lo.f, w.z, a2);
        hi.u = q01.y & 0xffff0000u;  a3 = fmaf(hi.f, w.z, a3);
        lo.u = q11.x << 16;          a0 = fmaf(lo.f, w.w, a0);
        hi.u = q11.x & 0xffff0000u;  a1 = fmaf(hi.f, w.w, a1);
        lo.u = q11.y << 16;          a2 = fmaf(lo.f, w.w, a2);
        hi.u = q11.y & 0xffff0000u;  a3 = fmaf(hi.f, w.w, a3);
    }

    uint2 o;
    o.x = (unsigned)f2bf(a0) | ((unsigned)f2bf(a1) << 16);
    o.y = (unsigned)f2bf(a2) | ((unsigned)f2bf(a3) << 16);
    *(uint2*)((unsigned short*)sampled + (size_t)row * 256 + h * 32 + c4 * 4) = o;
}

extern "C" void kernel_launch(void* const* d_in, const int* in_sizes, int n_in,
                              void* d_out, int out_size, void* d_ws, size_t ws_size,
                              hipStream_t stream)
{
    const float* query  = (const float*)d_in[0];
    const float* refpts = (const float*)d_in[1];
    const float* value  = (const float*)d_in[2];
    const float* Woff   = (const float*)d_in[4];
    const float* boff   = (const float*)d_in[5];
    const float* Wattn  = (const float*)d_in[6];
    const float* battn  = (const float*)d_in[7];
    const float* Wv     = (const float*)d_in[8];
    const float* bv     = (const float*)d_in[9];
    const float* Wout   = (const float*)d_in[10];
    const float* bout   = (const float*)d_in[11];
    float* out = (float*)d_out;

    // workspace (bf16 elements): 48.1 MB total
    constexpr size_t SZ_VHM = (size_t)2 * 8 * LV * 32;      // 6,806,528
    constexpr size_t SZ_OFF = (size_t)NROWS * 384;          // 10,209,792
    constexpr size_t SZ_ROW = (size_t)NROWS * 256;          // 6,806,528
    __hip_bfloat16* ws      = (__hip_bfloat16*)d_ws;
    __hip_bfloat16* vhm     = ws;
    __hip_bfloat16* offlog  = vhm + SZ_VHM;
    __hip_bfloat16* sampled = offlog + SZ_OFF;
    __hip_bfloat16* WT      = sampled + SZ_ROW;             // 896*256

    const int gblk = (NROWS + 31) / 32;   // 831
    const int sblk = NROWS / 4;           // 6647 (exact)

    hipLaunchKernelGGL(prep_weights, dim3(14, 4), dim3(256), 0, stream,
                       Wv, Woff, Wattn, Wout, WT);
    hipLaunchKernelGGL(gemm_vq, dim3(gblk, 2), dim3(256), 0, stream,
                       value, query, WT, bv, boff, battn, vhm, offlog, NROWS);
    hipLaunchKernelGGL(ms_sample, dim3(sblk), dim3(256), 0, stream,
                       vhm, offlog, refpts, sampled);
    hipLaunchKernelGGL(gemm_out_k, dim3(gblk), dim3(256), 0, stream,
                       sampled, WT + 640 * 256, bout, out, NROWS);
}

// Round 6
// 123.056 us; speedup vs baseline: 3.4739x; 1.1823x over previous
//
#include <hip/hip_runtime.h>
#include <hip/hip_bf16.h>
#include <math.h>

// Deformable DETR multi-scale deformable attention — MI355X (gfx950)
// B=2, Lq=Lv=13294, D=256, H=8, HD=32, L=4, P=4
// Levels (square): 100,50,25,13  starts {0,10000,12500,13125}

namespace {
constexpr int LQ    = 13294;
constexpr int LV    = 13294;
constexpr int NROWS = 2 * LQ;   // 26588
}

typedef __attribute__((ext_vector_type(8))) short short8;   // 8 x bf16
typedef __attribute__((ext_vector_type(4))) float f32x4;    // MFMA accumulator

__device__ inline float bf2f(unsigned u16) {
    union { unsigned u; float f; } c; c.u = u16 << 16; return c.f;
}
__device__ inline unsigned short f2bf(float f) {
    __hip_bfloat16 h = __float2bfloat16(f);
    return *reinterpret_cast<unsigned short*>(&h);
}

// ---------------------------------------------------------------------------
// Weight prep, fragment-major: WTf[ctile][kc][lane][8] bf16, where
// ctile = col>>4 over the concatenated [Wv^T|Woff^T|Wattn^T|Wout^T] (896 cols),
// kc = k>>5, lane = (col&15) | (((k>>3)&3)<<4), j = k&7.
// A wave's B-fragment load becomes base + lane*16B  (fully coalesced 1KB).
// ---------------------------------------------------------------------------
__global__ __launch_bounds__(256) void prep_weights(
    const float* __restrict__ Wv, const float* __restrict__ Woff,
    const float* __restrict__ Wattn, const float* __restrict__ Wout,
    __hip_bfloat16* __restrict__ WTf)
{
    const int c = blockIdx.x, k = threadIdx.x;
    float v;
    if (c < 256)      v = Wv[k * 256 + c];
    else if (c < 512) v = Woff[k * 256 + (c - 256)];
    else if (c < 640) v = Wattn[k * 128 + (c - 512)];
    else              v = Wout[k * 256 + (c - 640)];
    const int lane = (c & 15) | (((k >> 3) & 3) << 4);
    const size_t dst = ((size_t)((c >> 4) * 8 + (k >> 5)) * 64 + lane) * 8 + (k & 7);
    WTf[dst] = __float2bfloat16(v);
}

// ---------------------------------------------------------------------------
// GEMM core: Y[M][*] = X[M][256] @ W[256][N] + bias,  N = 4 waves * NT * 16.
// A staged (64 rows) in LDS as bf16; B-fragments loaded coalesced from WTf.
// Per wave: RT=4 row-tiles, NT col-tiles, 8 k-chunks -> 32*NT MFMA.
// OUTMODE 0: fp32 Y[rr*ldY + coloff + col]
//         1: bf16 Y[rr*ldY + coloff + col]
//         2: bf16 head-major vhm[((b*8+h)*LV + lv)*32 + cc]
// ---------------------------------------------------------------------------
template<int NT, int OUTMODE, bool A_FP32>
__device__ __forceinline__ void gemm_core(
    short (*As)[264], const void* __restrict__ Xv,
    const __hip_bfloat16* __restrict__ WTf, int ct0,
    const float* __restrict__ bias, void* __restrict__ Yv,
    int ldY, int coloff, int M, int bx)
{
    const int t  = threadIdx.x;
    const int r0 = bx * 64;

    // ---- stage A (64 rows x 256) into LDS as bf16, coalesced ----
    if (A_FP32) {
        const float* X = (const float*)Xv;
        #pragma unroll
        for (int i = 0; i < 16; ++i) {
            const int f4 = i * 256 + t;          // 4096 float4s
            int row = r0 + (f4 >> 6);
            if (row >= M) row = M - 1;
            const int col4 = f4 & 63;
            const float4 u = *(const float4*)(X + (size_t)row * 256 + col4 * 4);
            union { unsigned short us[4]; uint2 v; } p;
            p.us[0] = f2bf(u.x); p.us[1] = f2bf(u.y);
            p.us[2] = f2bf(u.z); p.us[3] = f2bf(u.w);
            *(uint2*)(&As[f4 >> 6][col4 * 4]) = p.v;
        }
    } else {
        const __hip_bfloat16* X = (const __hip_bfloat16*)Xv;
        #pragma unroll
        for (int i = 0; i < 8; ++i) {
            const int f8 = i * 256 + t;          // 2048 16B-chunks
            int row = r0 + (f8 >> 5);
            if (row >= M) row = M - 1;
            const int c16 = f8 & 31;
            *(short8*)(&As[f8 >> 5][c16 * 8]) =
                *(const short8*)(X + (size_t)row * 256 + c16 * 8);
        }
    }
    __syncthreads();

    const int lane = t & 63;
    const int wv   = t >> 6;
    const int r16  = lane & 15;
    const int koff = (lane >> 4) * 8;

    f32x4 acc[4][NT];
    #pragma unroll
    for (int rt = 0; rt < 4; ++rt)
        #pragma unroll
        for (int nt = 0; nt < NT; ++nt)
            #pragma unroll
            for (int j = 0; j < 4; ++j) acc[rt][nt][j] = 0.f;

    #pragma unroll
    for (int kc = 0; kc < 8; ++kc) {
        short8 a[4];
        #pragma unroll
        for (int rt = 0; rt < 4; ++rt)
            a[rt] = *(const short8*)(&As[rt * 16 + r16][kc * 32 + koff]);
        #pragma unroll
        for (int nt = 0; nt < NT; ++nt) {
            const int ct = ct0 + wv * NT + nt;
            const short8 bfr =
                *(const short8*)(WTf + ((size_t)(ct * 8 + kc) * 64 + lane) * 8);
            #pragma unroll
            for (int rt = 0; rt < 4; ++rt)
                acc[rt][nt] = __builtin_amdgcn_mfma_f32_16x16x32_bf16(
                    a[rt], bfr, acc[rt][nt], 0, 0, 0);
        }
    }

    const int orow = (lane >> 4) * 4;
    #pragma unroll
    for (int rt = 0; rt < 4; ++rt)
    #pragma unroll
    for (int nt = 0; nt < NT; ++nt) {
        const int lcol = wv * (NT * 16) + nt * 16 + r16;
        const float bb = bias[lcol];
        #pragma unroll
        for (int j = 0; j < 4; ++j) {
            const int rr = r0 + rt * 16 + orow + j;
            if (rr < M) {
                const float v = acc[rt][nt][j] + bb;
                if (OUTMODE == 0) {
                    ((float*)Yv)[(size_t)rr * ldY + coloff + lcol] = v;
                } else if (OUTMODE == 1) {
                    ((__hip_bfloat16*)Yv)[(size_t)rr * ldY + coloff + lcol] =
                        __float2bfloat16(v);
                } else {
                    const int b  = (rr >= LQ) ? 1 : 0;
                    const int lv = rr - b * LQ;
                    const int h  = lcol >> 5, cc = lcol & 31;
                    ((__hip_bfloat16*)Yv)[(((size_t)(b * 8 + h)) * LV + lv) * 32 + cc] =
                        __float2bfloat16(v);
                }
            }
        }
    }
}

// fused: y=0 value->vhm (N=256) | y=1 query->offsets (N=256) | y=2 query->logits (N=128)
__global__ __launch_bounds__(256) void gemm_vq(
    const float* __restrict__ value, const float* __restrict__ query,
    const __hip_bfloat16* __restrict__ WTf,
    const float* __restrict__ bv, const float* __restrict__ boff,
    const float* __restrict__ battn,
    __hip_bfloat16* __restrict__ vhm, __hip_bfloat16* __restrict__ offlog, int M)
{
    __shared__ short As[64][264];
    if (blockIdx.y == 0)
        gemm_core<4, 2, true>(As, value, WTf, 0,  bv,    vhm,    0,   0,   M, blockIdx.x);
    else if (blockIdx.y == 1)
        gemm_core<4, 1, true>(As, query, WTf, 16, boff,  offlog, 384, 0,   M, blockIdx.x);
    else
        gemm_core<2, 1, true>(As, query, WTf, 32, battn, offlog, 384, 256, M, blockIdx.x);
}

__global__ __launch_bounds__(256) void gemm_out_k(
    const __hip_bfloat16* __restrict__ sampled, const __hip_bfloat16* __restrict__ WTf,
    const float* __restrict__ bout, float* __restrict__ out, int M)
{
    __shared__ short As[64][264];
    gemm_core<4, 0, false>(As, sampled, WTf, 40, bout, out, 256, 0, M, blockIdx.x);
}

// ---------------------------------------------------------------------------
// ms_sample v5 (unchanged from R5): 4 rows per 256-thread block.
// Phase 1: per (row,head,sample) -> 4 clamped corner offsets + 4 attn*bilinear
//   weights (zeroed OOB) -> LDS. Phase 2: thread = (rl,h,c4), 4 channels;
//   per sample: 2 broadcast LDS reads + 4 unconditional 8B gathers + FMA.
// ---------------------------------------------------------------------------
__global__ __launch_bounds__(256) void ms_sample(
    const __hip_bfloat16* __restrict__ vhm, const __hip_bfloat16* __restrict__ offlog,
    const float* __restrict__ refpts, __hip_bfloat16* __restrict__ sampled)
{
    __shared__ char params[4][16][304];

    const int t    = threadIdx.x;
    const int row0 = blockIdx.x * 4;

    #pragma unroll
    for (int it = 0; it < 2; ++it) {
        const int sid = it * 256 + t;
        const int rl  = sid >> 7;
        const int h   = (sid >> 4) & 7;
        const int s   = sid & 15;
        const int row = row0 + rl;
        const int l   = s >> 2;
        const int wl  = (l == 0) ? 100 : (l == 1) ? 50 : (l == 2) ? 25 : 13;
        const int st  = (l == 0) ? 0 : (l == 1) ? 10000 : (l == 2) ? 12500 : 13125;
        const float wlf = (float)wl;

        const unsigned short* ol = (const unsigned short*)offlog + (size_t)row * 384;
        const unsigned uoff = *(const unsigned*)(ol + h * 32 + s * 2);
        const float ox = bf2f(uoff & 0xffffu), oy = bf2f(uoff >> 16);
        const float lg = bf2f(ol[256 + h * 16 + s]);
        const float2 rf = *(const float2*)(refpts + (size_t)row * 8 + l * 2);

        float m = lg;
        #pragma unroll
        for (int o = 8; o > 0; o >>= 1) m = fmaxf(m, __shfl_xor(m, o, 16));
        const float e = __expf(lg - m);
        float ssum = e;
        #pragma unroll
        for (int o = 8; o > 0; o >>= 1) ssum += __shfl_xor(ssum, o, 16);
        const float a = e / ssum;

        const float x = fmaf(rf.x, wlf, ox) - 0.5f;
        const float y = fmaf(rf.y, wlf, oy) - 0.5f;
        const float x0f = floorf(x), y0f = floorf(y);
        const int   x0 = (int)x0f, y0 = (int)y0f;
        const float wx1 = x - x0f, wx0 = 1.f - wx1;
        const float wy1 = y - y0f, wy0 = 1.f - wy1;
        const bool xv0 = (unsigned)x0       < (unsigned)wl;
        const bool xv1 = (unsigned)(x0 + 1) < (unsigned)wl;
        const bool yv0 = (unsigned)y0       < (unsigned)wl;
        const bool yv1 = (unsigned)(y0 + 1) < (unsigned)wl;
        const float ax0 = a * wx0, ax1 = a * wx1;
        float w00 = ax0 * wy0, w10 = ax1 * wy0;
        float w01 = ax0 * wy1, w11 = ax1 * wy1;
        w00 = (xv0 && yv0) ? w00 : 0.f;
        w10 = (xv1 && yv0) ? w10 : 0.f;
        w01 = (xv0 && yv1) ? w01 : 0.f;
        w11 = (xv1 && yv1) ? w11 : 0.f;
        const int cx0 = min(max(x0, 0), wl - 1);
        const int cx1 = min(max(x0 + 1, 0), wl - 1);
        const int cy0 = min(max(y0, 0), wl - 1);
        const int cy1 = min(max(y0 + 1, 0), wl - 1);
        const int r0b = (st + cy0 * wl) * 64;
        const int r1b = (st + cy1 * wl) * 64;
        uint4  offs; offs.x = r0b + cx0 * 64; offs.y = r0b + cx1 * 64;
                     offs.z = r1b + cx0 * 64; offs.w = r1b + cx1 * 64;
        float4 wv4;  wv4.x = w00; wv4.y = w10; wv4.z = w01; wv4.w = w11;
        char* pe = &params[rl][s][h * 32];
        *(uint4*)pe         = offs;
        *(float4*)(pe + 16) = wv4;
    }
    __syncthreads();

    const int rl  = t >> 6;
    const int h   = (t >> 3) & 7;
    const int c4  = t & 7;
    const int row = row0 + rl;
    const int b   = (row >= LQ) ? 1 : 0;
    const char* vbase = (const char*)vhm + ((size_t)((b << 3) + h) * LV) * 64 + c4 * 8;

    float a0 = 0.f, a1 = 0.f, a2 = 0.f, a3 = 0.f;
    #pragma unroll
    for (int s = 0; s < 16; ++s) {
        const char* pe = &params[rl][s][h * 32];
        const uint4  offs = *(const uint4*)pe;
        const float4 w    = *(const float4*)(pe + 16);
        const uint2 q00 = *(const uint2*)(vbase + offs.x);
        const uint2 q10 = *(const uint2*)(vbase + offs.y);
        const uint2 q01 = *(const uint2*)(vbase + offs.z);
        const uint2 q11 = *(const uint2*)(vbase + offs.w);
        union { unsigned u; float f; } lo, hi;
        lo.u = q00.x << 16;          a0 = fmaf(lo.f, w.x, a0);
        hi.u = q00.x & 0xffff0000u;  a1 = fmaf(hi.f, w.x, a1);
        lo.u = q00.y << 16;          a2 = fmaf(lo.f, w.x, a2);
        hi.u = q00.y & 0xffff0000u;  a3 = fmaf(hi.f, w.x, a3);
        lo.u = q10.x << 16;          a0 = fmaf(lo.f, w.y, a0);
        hi.u = q10.x & 0xffff0000u;  a1 = fmaf(hi.f, w.y, a1);
        lo.u = q10.y << 16;          a2 = fmaf(lo.f, w.y, a2);
        hi.u = q10.y & 0xffff0000u;  a3 = fmaf(hi.f, w.y, a3);
        lo.u = q01.x << 16;          a0 = fmaf(lo.f, w.z, a0);
        hi.u = q01.x & 0xffff0000u;  a1 = fmaf(hi.f, w.z, a1);
        lo.u = q01.y << 16;          a2 = fmaf(lo.f, w.z, a2);
        hi.u = q01.y & 0xffff0000u;  a3 = fmaf(hi.f, w.z, a3);
        lo.u = q11.x << 16;          a0 = fmaf(lo.f, w.w, a0);
        hi.u = q11.x & 0xffff0000u;  a1 = fmaf(hi.f, w.w, a1);
        lo.u = q11.y << 16;          a2 = fmaf(lo.f, w.w, a2);
        hi.u = q11.y & 0xffff0000u;  a3 = fmaf(hi.f, w.w, a3);
    }

    uint2 o;
    o.x = (unsigned)f2bf(a0) | ((unsigned)f2bf(a1) << 16);
    o.y = (unsigned)f2bf(a2) | ((unsigned)f2bf(a3) << 16);
    *(uint2*)((unsigned short*)sampled + (size_t)row * 256 + h * 32 + c4 * 4) = o;
}

extern "C" void kernel_launch(void* const* d_in, const int* in_sizes, int n_in,
                              void* d_out, int out_size, void* d_ws, size_t ws_size,
                              hipStream_t stream)
{
    const float* query  = (const float*)d_in[0];
    const float* refpts = (const float*)d_in[1];
    const float* value  = (const float*)d_in[2];
    const float* Woff   = (const float*)d_in[4];
    const float* boff   = (const float*)d_in[5];
    const float* Wattn  = (const float*)d_in[6];
    const float* battn  = (const float*)d_in[7];
    const float* Wv     = (const float*)d_in[8];
    const float* bv     = (const float*)d_in[9];
    const float* Wout   = (const float*)d_in[10];
    const float* bout   = (const float*)d_in[11];
    float* out = (float*)d_out;

    // workspace (bf16 elements): 48.1 MB total
    constexpr size_t SZ_VHM = (size_t)2 * 8 * LV * 32;      // 6,806,528
    constexpr size_t SZ_OFF = (size_t)NROWS * 384;          // 10,209,792
    constexpr size_t SZ_ROW = (size_t)NROWS * 256;          // 6,806,528
    __hip_bfloat16* ws      = (__hip_bfloat16*)d_ws;
    __hip_bfloat16* vhm     = ws;
    __hip_bfloat16* offlog  = vhm + SZ_VHM;
    __hip_bfloat16* sampled = offlog + SZ_OFF;
    __hip_bfloat16* WTf     = sampled + SZ_ROW;             // 896*256

    const int gblk = (NROWS + 63) / 64;   // 416
    const int sblk = NROWS / 4;           // 6647 (exact)

    hipLaunchKernelGGL(prep_weights, dim3(896), dim3(256), 0, stream,
                       Wv, Woff, Wattn, Wout, WTf);
    hipLaunchKernelGGL(gemm_vq, dim3(gblk, 3), dim3(256), 0, stream,
                       value, query, WTf, bv, boff, battn, vhm, offlog, NROWS);
    hipLaunchKernelGGL(ms_sample, dim3(sblk), dim3(256), 0, stream,
                       vhm, offlog, refpts, sampled);
    hipLaunchKernelGGL(gemm_out_k, dim3(gblk), dim3(256), 0, stream,
                       sampled, WTf, bout, out, NROWS);
}

// Round 7
// 118.293 us; speedup vs baseline: 3.6138x; 1.0403x over previous
//
#include <hip/hip_runtime.h>
#include <hip/hip_bf16.h>
#include <math.h>

// Deformable DETR multi-scale deformable attention — MI355X (gfx950)
// B=2, Lq=Lv=13294, D=256, H=8, HD=32, L=4, P=4
// Levels (square): 100,50,25,13  starts {0,10000,12500,13125}

namespace {
constexpr int LQ    = 13294;
constexpr int LV    = 13294;
constexpr int NROWS = 2 * LQ;   // 26588
}

typedef __attribute__((ext_vector_type(8))) short short8;   // 8 x bf16
typedef __attribute__((ext_vector_type(4))) float f32x4;    // MFMA accumulator

__device__ inline float bf2f(unsigned u16) {
    union { unsigned u; float f; } c; c.u = u16 << 16; return c.f;
}
__device__ inline unsigned short f2bf(float f) {
    __hip_bfloat16 h = __float2bfloat16(f);
    return *reinterpret_cast<unsigned short*>(&h);
}

// ---------------------------------------------------------------------------
// Weight prep, fragment-major: WTf[ctile][kc][lane][8] bf16 over the
// concatenated [Wv^T|Woff^T|Wattn^T|Wout^T] (896 cols).
// ---------------------------------------------------------------------------
__global__ __launch_bounds__(256) void prep_weights(
    const float* __restrict__ Wv, const float* __restrict__ Woff,
    const float* __restrict__ Wattn, const float* __restrict__ Wout,
    __hip_bfloat16* __restrict__ WTf)
{
    const int c = blockIdx.x, k = threadIdx.x;
    float v;
    if (c < 256)      v = Wv[k * 256 + c];
    else if (c < 512) v = Woff[k * 256 + (c - 256)];
    else if (c < 640) v = Wattn[k * 128 + (c - 512)];
    else              v = Wout[k * 256 + (c - 640)];
    const int lane = (c & 15) | (((k >> 3) & 3) << 4);
    const size_t dst = ((size_t)((c >> 4) * 8 + (k >> 5)) * 64 + lane) * 8 + (k & 7);
    WTf[dst] = __float2bfloat16(v);
}

// ---------------------------------------------------------------------------
// GEMM core (as R6, fragment-major B): 64 rows/block, RT=4, NT col-tiles.
// ---------------------------------------------------------------------------
template<int NT, int OUTMODE, bool A_FP32>
__device__ __forceinline__ void gemm_core(
    short (*As)[264], const void* __restrict__ Xv,
    const __hip_bfloat16* __restrict__ WTf, int ct0,
    const float* __restrict__ bias, void* __restrict__ Yv,
    int ldY, int coloff, int M, int bx)
{
    const int t  = threadIdx.x;
    const int r0 = bx * 64;

    if (A_FP32) {
        const float* X = (const float*)Xv;
        #pragma unroll
        for (int i = 0; i < 16; ++i) {
            const int f4 = i * 256 + t;          // 4096 float4s
            int row = r0 + (f4 >> 6);
            if (row >= M) row = M - 1;
            const int col4 = f4 & 63;
            const float4 u = *(const float4*)(X + (size_t)row * 256 + col4 * 4);
            union { unsigned short us[4]; uint2 v; } p;
            p.us[0] = f2bf(u.x); p.us[1] = f2bf(u.y);
            p.us[2] = f2bf(u.z); p.us[3] = f2bf(u.w);
            *(uint2*)(&As[f4 >> 6][col4 * 4]) = p.v;
        }
    } else {
        const __hip_bfloat16* X = (const __hip_bfloat16*)Xv;
        #pragma unroll
        for (int i = 0; i < 8; ++i) {
            const int f8 = i * 256 + t;          // 2048 16B-chunks
            int row = r0 + (f8 >> 5);
            if (row >= M) row = M - 1;
            const int c16 = f8 & 31;
            *(short8*)(&As[f8 >> 5][c16 * 8]) =
                *(const short8*)(X + (size_t)row * 256 + c16 * 8);
        }
    }
    __syncthreads();

    const int lane = t & 63;
    const int wv   = t >> 6;
    const int r16  = lane & 15;
    const int koff = (lane >> 4) * 8;

    f32x4 acc[4][NT];
    #pragma unroll
    for (int rt = 0; rt < 4; ++rt)
        #pragma unroll
        for (int nt = 0; nt < NT; ++nt)
            #pragma unroll
            for (int j = 0; j < 4; ++j) acc[rt][nt][j] = 0.f;

    #pragma unroll
    for (int kc = 0; kc < 8; ++kc) {
        short8 a[4];
        #pragma unroll
        for (int rt = 0; rt < 4; ++rt)
            a[rt] = *(const short8*)(&As[rt * 16 + r16][kc * 32 + koff]);
        #pragma unroll
        for (int nt = 0; nt < NT; ++nt) {
            const int ct = ct0 + wv * NT + nt;
            const short8 bfr =
                *(const short8*)(WTf + ((size_t)(ct * 8 + kc) * 64 + lane) * 8);
            #pragma unroll
            for (int rt = 0; rt < 4; ++rt)
                acc[rt][nt] = __builtin_amdgcn_mfma_f32_16x16x32_bf16(
                    a[rt], bfr, acc[rt][nt], 0, 0, 0);
        }
    }

    const int orow = (lane >> 4) * 4;
    #pragma unroll
    for (int rt = 0; rt < 4; ++rt)
    #pragma unroll
    for (int nt = 0; nt < NT; ++nt) {
        const int lcol = wv * (NT * 16) + nt * 16 + r16;
        const float bb = bias[lcol];
        #pragma unroll
        for (int j = 0; j < 4; ++j) {
            const int rr = r0 + rt * 16 + orow + j;
            if (rr < M) {
                const float v = acc[rt][nt][j] + bb;
                if (OUTMODE == 0) {
                    ((float*)Yv)[(size_t)rr * ldY + coloff + lcol] = v;
                } else if (OUTMODE == 1) {
                    ((__hip_bfloat16*)Yv)[(size_t)rr * ldY + coloff + lcol] =
                        __float2bfloat16(v);
                } else {
                    const int b  = (rr >= LQ) ? 1 : 0;
                    const int lv = rr - b * LQ;
                    const int h  = lcol >> 5, cc = lcol & 31;
                    ((__hip_bfloat16*)Yv)[(((size_t)(b * 8 + h)) * LV + lv) * 32 + cc] =
                        __float2bfloat16(v);
                }
            }
        }
    }
}

// fused: y=0 value->vhm (N=256) | y=1 query->offsets (N=256) | y=2 query->logits (N=128)
__global__ __launch_bounds__(256, 2) void gemm_vq(
    const float* __restrict__ value, const float* __restrict__ query,
    const __hip_bfloat16* __restrict__ WTf,
    const float* __restrict__ bv, const float* __restrict__ boff,
    const float* __restrict__ battn,
    __hip_bfloat16* __restrict__ vhm, __hip_bfloat16* __restrict__ offlog, int M)
{
    __shared__ short As[64][264];
    if (blockIdx.y == 0)
        gemm_core<4, 2, true>(As, value, WTf, 0,  bv,    vhm,    0,   0,   M, blockIdx.x);
    else if (blockIdx.y == 1)
        gemm_core<4, 1, true>(As, query, WTf, 16, boff,  offlog, 384, 0,   M, blockIdx.x);
    else
        gemm_core<2, 1, true>(As, query, WTf, 32, battn, offlog, 384, 256, M, blockIdx.x);
}

__global__ __launch_bounds__(256, 2) void gemm_out_k(
    const __hip_bfloat16* __restrict__ sampled, const __hip_bfloat16* __restrict__ WTf,
    const float* __restrict__ bout, float* __restrict__ out, int M)
{
    __shared__ short As[64][264];
    gemm_core<4, 0, false>(As, sampled, WTf, 40, bout, out, 256, 0, M, blockIdx.x);
}

// ---------------------------------------------------------------------------
// ms_sample v6: head-partitioned for XCD-L2 locality.
// Block = 32 rows x 1 head; h = blockIdx.x & 7  =>  (assuming round-robin
// block->XCD dispatch) XCD x only touches head planes (0,x),(1,x) = 1.7 MB,
// which is L2-resident. Same per-row instruction counts as v5.
// Phase 1: 512 param sets (row, s): 4 clamped corner offsets + 4
//   attn*bilinear weights (zeroed OOB) -> LDS (stride 544B: 2-way = free).
// Phase 2: thread = (row, c4): per sample 2 broadcast LDS b128 reads + 4
//   unconditional 8B gathers (8 lanes x 8B = one 64B line per corner) + FMA.
// ---------------------------------------------------------------------------
__global__ __launch_bounds__(256) void ms_sample(
    const __hip_bfloat16* __restrict__ vhm, const __hip_bfloat16* __restrict__ offlog,
    const float* __restrict__ refpts, __hip_bfloat16* __restrict__ sampled)
{
    __shared__ char params[32][544];   // [row][s*32B], 544 = 17*32 (bank-spread)

    const int t  = threadIdx.x;
    const int h  = blockIdx.x & 7;
    const int r0 = (blockIdx.x >> 3) * 32;

    // ---------------- phase 1 ----------------
    #pragma unroll
    for (int it = 0; it < 2; ++it) {
        const int sid  = it * 256 + t;
        const int rl   = sid >> 4;          // 0..31
        const int s    = sid & 15;
        int row = r0 + rl;
        if (row >= NROWS) row = NROWS - 1;  // clamp (reads only; params unused)
        const int l   = s >> 2;
        const int wl  = (l == 0) ? 100 : (l == 1) ? 50 : (l == 2) ? 25 : 13;
        const int st  = (l == 0) ? 0 : (l == 1) ? 10000 : (l == 2) ? 12500 : 13125;
        const float wlf = (float)wl;

        const unsigned short* ol = (const unsigned short*)offlog + (size_t)row * 384;
        const unsigned uoff = *(const unsigned*)(ol + h * 32 + s * 2);
        const float ox = bf2f(uoff & 0xffffu), oy = bf2f(uoff >> 16);
        const float lg = bf2f(ol[256 + h * 16 + s]);
        const float2 rf = *(const float2*)(refpts + (size_t)row * 8 + l * 2);

        // softmax over the 16 lanes of this (row, h)
        float m = lg;
        #pragma unroll
        for (int o = 8; o > 0; o >>= 1) m = fmaxf(m, __shfl_xor(m, o, 16));
        const float e = __expf(lg - m);
        float ssum = e;
        #pragma unroll
        for (int o = 8; o > 0; o >>= 1) ssum += __shfl_xor(ssum, o, 16);
        const float a = e / ssum;

        const float x = fmaf(rf.x, wlf, ox) - 0.5f;
        const float y = fmaf(rf.y, wlf, oy) - 0.5f;
        const float x0f = floorf(x), y0f = floorf(y);
        const int   x0 = (int)x0f, y0 = (int)y0f;
        const float wx1 = x - x0f, wx0 = 1.f - wx1;
        const float wy1 = y - y0f, wy0 = 1.f - wy1;
        const bool xv0 = (unsigned)x0       < (unsigned)wl;
        const bool xv1 = (unsigned)(x0 + 1) < (unsigned)wl;
        const bool yv0 = (unsigned)y0       < (unsigned)wl;
        const bool yv1 = (unsigned)(y0 + 1) < (unsigned)wl;
        const float ax0 = a * wx0, ax1 = a * wx1;
        float w00 = ax0 * wy0, w10 = ax1 * wy0;
        float w01 = ax0 * wy1, w11 = ax1 * wy1;
        w00 = (xv0 && yv0) ? w00 : 0.f;
        w10 = (xv1 && yv0) ? w10 : 0.f;
        w01 = (xv0 && yv1) ? w01 : 0.f;
        w11 = (xv1 && yv1) ? w11 : 0.f;
        const int cx0 = min(max(x0, 0), wl - 1);
        const int cx1 = min(max(x0 + 1, 0), wl - 1);
        const int cy0 = min(max(y0, 0), wl - 1);
        const int cy1 = min(max(y0 + 1, 0), wl - 1);
        const int r0b = (st + cy0 * wl) * 64;   // byte offsets into head plane
        const int r1b = (st + cy1 * wl) * 64;
        uint4  offs; offs.x = r0b + cx0 * 64; offs.y = r0b + cx1 * 64;
                     offs.z = r1b + cx0 * 64; offs.w = r1b + cx1 * 64;
        float4 wv4;  wv4.x = w00; wv4.y = w10; wv4.z = w01; wv4.w = w11;
        char* pe = &params[rl][s * 32];
        *(uint4*)pe         = offs;
        *(float4*)(pe + 16) = wv4;
    }
    __syncthreads();

    // ---------------- phase 2 ----------------
    const int rl  = t >> 3;        // 0..31
    const int c4  = t & 7;
    const int row = r0 + rl;
    const int b   = (row >= LQ) ? 1 : 0;
    const char* vbase = (const char*)vhm + ((size_t)((b << 3) + h) * LV) * 64 + c4 * 8;

    float a0 = 0.f, a1 = 0.f, a2 = 0.f, a3 = 0.f;
    #pragma unroll
    for (int s = 0; s < 16; ++s) {
        const char* pe = &params[rl][s * 32];
        const uint4  offs = *(const uint4*)pe;
        const float4 w    = *(const float4*)(pe + 16);
        const uint2 q00 = *(const uint2*)(vbase + offs.x);
        const uint2 q10 = *(const uint2*)(vbase + offs.y);
        const uint2 q01 = *(const uint2*)(vbase + offs.z);
        const uint2 q11 = *(const uint2*)(vbase + offs.w);
        union { unsigned u; float f; } lo, hi;
        lo.u = q00.x << 16;          a0 = fmaf(lo.f, w.x, a0);
        hi.u = q00.x & 0xffff0000u;  a1 = fmaf(hi.f, w.x, a1);
        lo.u = q00.y << 16;          a2 = fmaf(lo.f, w.x, a2);
        hi.u = q00.y & 0xffff0000u;  a3 = fmaf(hi.f, w.x, a3);
        lo.u = q10.x << 16;          a0 = fmaf(lo.f, w.y, a0);
        hi.u = q10.x & 0xffff0000u;  a1 = fmaf(hi.f, w.y, a1);
        lo.u = q10.y << 16;          a2 = fmaf(lo.f, w.y, a2);
        hi.u = q10.y & 0xffff0000u;  a3 = fmaf(hi.f, w.y, a3);
        lo.u = q01.x << 16;          a0 = fmaf(lo.f, w.z, a0);
        hi.u = q01.x & 0xffff0000u;  a1 = fmaf(hi.f, w.z, a1);
        lo.u = q01.y << 16;          a2 = fmaf(lo.f, w.z, a2);
        hi.u = q01.y & 0xffff0000u;  a3 = fmaf(hi.f, w.z, a3);
        lo.u = q11.x << 16;          a0 = fmaf(lo.f, w.w, a0);
        hi.u = q11.x & 0xffff0000u;  a1 = fmaf(hi.f, w.w, a1);
        lo.u = q11.y << 16;          a2 = fmaf(lo.f, w.w, a2);
        hi.u = q11.y & 0xffff0000u;  a3 = fmaf(hi.f, w.w, a3);
    }

    if (row < NROWS) {
        uint2 o;
        o.x = (unsigned)f2bf(a0) | ((unsigned)f2bf(a1) << 16);
        o.y = (unsigned)f2bf(a2) | ((unsigned)f2bf(a3) << 16);
        *(uint2*)((unsigned short*)sampled + (size_t)row * 256 + h * 32 + c4 * 4) = o;
    }
}

extern "C" void kernel_launch(void* const* d_in, const int* in_sizes, int n_in,
                              void* d_out, int out_size, void* d_ws, size_t ws_size,
                              hipStream_t stream)
{
    const float* query  = (const float*)d_in[0];
    const float* refpts = (const float*)d_in[1];
    const float* value  = (const float*)d_in[2];
    const float* Woff   = (const float*)d_in[4];
    const float* boff   = (const float*)d_in[5];
    const float* Wattn  = (const float*)d_in[6];
    const float* battn  = (const float*)d_in[7];
    const float* Wv     = (const float*)d_in[8];
    const float* bv     = (const float*)d_in[9];
    const float* Wout   = (const float*)d_in[10];
    const float* bout   = (const float*)d_in[11];
    float* out = (float*)d_out;

    // workspace (bf16 elements): 48.1 MB total
    constexpr size_t SZ_VHM = (size_t)2 * 8 * LV * 32;      // 6,806,528
    constexpr size_t SZ_OFF = (size_t)NROWS * 384;          // 10,209,792
    constexpr size_t SZ_ROW = (size_t)NROWS * 256;          // 6,806,528
    __hip_bfloat16* ws      = (__hip_bfloat16*)d_ws;
    __hip_bfloat16* vhm     = ws;
    __hip_bfloat16* offlog  = vhm + SZ_VHM;
    __hip_bfloat16* sampled = offlog + SZ_OFF;
    __hip_bfloat16* WTf     = sampled + SZ_ROW;             // 896*256

    const int gblk = (NROWS + 63) / 64;   // 416
    const int sblk = ((NROWS + 31) / 32) * 8;   // 831 row-tiles x 8 heads = 6648

    hipLaunchKernelGGL(prep_weights, dim3(896), dim3(256), 0, stream,
                       Wv, Woff, Wattn, Wout, WTf);
    hipLaunchKernelGGL(gemm_vq, dim3(gblk, 3), dim3(256), 0, stream,
                       value, query, WTf, bv, boff, battn, vhm, offlog, NROWS);
    hipLaunchKernelGGL(ms_sample, dim3(sblk), dim3(256), 0, stream,
                       vhm, offlog, refpts, sampled);
    hipLaunchKernelGGL(gemm_out_k, dim3(gblk), dim3(256), 0, stream,
                       sampled, WTf, bout, out, NROWS);
}